// Round 6
// baseline (278.235 us; speedup 1.0000x reference)
//
#include <hip/hip_runtime.h>
#include <stdint.h>

// EETQLinear w8a16: out[m,n] = (sum_k x[m,k]*wq[k,n]) * scale[n] + bias[n]
// M=8192, K=4096, N=4096. Dtypes (r3/r4-verified): x/scale/bias/out f32, wq int32.
// v6: r5's 256x256 8-phase GEMM + latency hiding:
//   - ping-pong A-frag reg sets, next-phase ds_reads issued under current MFMA,
//     counted lgkmcnt(4) waits (rule-18 sched_barrier after each wait)
//   - stages redistributed 1/2/1/0 per K-tile so VMC2 never stalls (>=2-phase lead)

typedef __attribute__((ext_vector_type(4))) float     f32x4;
typedef __attribute__((ext_vector_type(8))) _Float16  f16x8;

#define M_DIM 8192
#define N_DIM 4096
#define K_DIM 4096

// ---------------- prologue kernels (r4-verified) ----------------
__global__ __launch_bounds__(256) void convert_x_to_f16(const float* __restrict__ x,
                                                        _Float16* __restrict__ Xh) {
    const size_t i = ((size_t)blockIdx.x * 256 + threadIdx.x) * 8;
    float4 v0 = *(const float4*)(x + i);
    float4 v1 = *(const float4*)(x + i + 4);
    f16x8 h;
    h[0] = (_Float16)v0.x; h[1] = (_Float16)v0.y; h[2] = (_Float16)v0.z; h[3] = (_Float16)v0.w;
    h[4] = (_Float16)v1.x; h[5] = (_Float16)v1.y; h[6] = (_Float16)v1.z; h[7] = (_Float16)v1.w;
    *(f16x8*)(Xh + i) = h;
}

__global__ __launch_bounds__(256) void dequant_w_to_f16(const int* __restrict__ wq,
                                                        _Float16* __restrict__ Wt) {
    __shared__ _Float16 tile[64][65];
    const int n0 = blockIdx.x * 64;
    const int k0 = blockIdx.y * 64;
    const int t  = threadIdx.x;
    const int r  = t >> 2;
    const int c0 = (t & 3) * 16;
    const int* src = wq + (size_t)(k0 + r) * N_DIM + n0 + c0;
#pragma unroll
    for (int j = 0; j < 4; ++j) {
        int4 q = *(const int4*)(src + j * 4);
        tile[c0 + j * 4 + 0][r] = (_Float16)q.x;
        tile[c0 + j * 4 + 1][r] = (_Float16)q.y;
        tile[c0 + j * 4 + 2][r] = (_Float16)q.z;
        tile[c0 + j * 4 + 3][r] = (_Float16)q.w;
    }
    __syncthreads();
    const int nn  = t >> 2;
    const int cc0 = (t & 3) * 16;
    _Float16 vals[16] __attribute__((aligned(16)));
#pragma unroll
    for (int j = 0; j < 16; ++j) vals[j] = tile[nn][cc0 + j];
    _Float16* dst = Wt + (size_t)(n0 + nn) * K_DIM + k0 + cc0;
    *(float4*)(dst + 0) = *(const float4*)(vals + 0);
    *(float4*)(dst + 8) = *(const float4*)(vals + 8);
}

// ---------------- 8-phase 256x256 GEMM ----------------
#define AS1C(p) (const __attribute__((address_space(1))) void*)(p)
#define AS3C(p) (__attribute__((address_space(3))) void*)(p)

#define STAGE_A(arr, h, tile) do {                                                    \
    __builtin_amdgcn_global_load_lds(                                                 \
        AS1C(aStageBase + (size_t)((h) * 128) * K_DIM + (tile) * 64),                 \
        AS3C((char*)(arr) + (h) * 16384 + t * 16), 16, 0, 0);                         \
    __builtin_amdgcn_global_load_lds(                                                 \
        AS1C(aStageBase + (size_t)((h) * 128 + 64) * K_DIM + (tile) * 64),            \
        AS3C((char*)(arr) + (h) * 16384 + 8192 + t * 16), 16, 0, 0);                  \
} while (0)

#define STAGE_B(arr, h, tile) do {                                                    \
    __builtin_amdgcn_global_load_lds(                                                 \
        AS1C(bStageBase + (size_t)((h) * 128) * K_DIM + (tile) * 64),                 \
        AS3C((char*)(arr) + (h) * 16384 + t * 16), 16, 0, 0);                         \
    __builtin_amdgcn_global_load_lds(                                                 \
        AS1C(bStageBase + (size_t)((h) * 128 + 64) * K_DIM + (tile) * 64),            \
        AS3C((char*)(arr) + (h) * 16384 + 8192 + t * 16), 16, 0, 0);                  \
} while (0)

#define DSR(dst, addr, IMM) \
    asm volatile("ds_read_b128 %0, %1 offset:%c2" : "=v"(dst) : "v"(addr), "i"(IMM))

// A-quadrant Q (rows Q*32 + {0..15, 16..31} relative to wave) into reg set S
#define DSRA(S, Q, A0, A1)                   \
    DSR(S[0][0], A0, (Q) * 4096);            \
    DSR(S[0][1], A1, (Q) * 4096);            \
    DSR(S[1][0], A0, (Q) * 4096 + 2048);     \
    DSR(S[1][1], A1, (Q) * 4096 + 2048)

#define DSRB(BA0, BA1)                       \
    DSR(bf[0][0], BA0, 0);    DSR(bf[0][1], BA1, 0);    \
    DSR(bf[1][0], BA0, 2048); DSR(bf[1][1], BA1, 2048); \
    DSR(bf[2][0], BA0, 4096); DSR(bf[2][1], BA1, 4096); \
    DSR(bf[3][0], BA0, 6144); DSR(bf[3][1], BA1, 6144)

#define MMS(S, AI, N)                                                                 \
    acc[AI][N] = __builtin_amdgcn_mfma_f32_16x16x32_f16(S[(AI) & 1][0], bf[N][0],     \
                                                        acc[AI][N], 0, 0, 0);         \
    acc[AI][N] = __builtin_amdgcn_mfma_f32_16x16x32_f16(S[(AI) & 1][1], bf[N][1],     \
                                                        acc[AI][N], 0, 0, 0)

#define MFMA16(Q, S)                                                  \
    MMS(S, (Q) * 2 + 0, 0); MMS(S, (Q) * 2 + 0, 1);                   \
    MMS(S, (Q) * 2 + 0, 2); MMS(S, (Q) * 2 + 0, 3);                   \
    MMS(S, (Q) * 2 + 1, 0); MMS(S, (Q) * 2 + 1, 1);                   \
    MMS(S, (Q) * 2 + 1, 2); MMS(S, (Q) * 2 + 1, 3)

#define BARR()  __builtin_amdgcn_s_barrier()
#define SB0()   __builtin_amdgcn_sched_barrier(0)
#define LGKM0() do { asm volatile("s_waitcnt lgkmcnt(0)" ::: "memory"); SB0(); } while (0)
#define LGKM4() do { asm volatile("s_waitcnt lgkmcnt(4)" ::: "memory"); SB0(); } while (0)
#define VMC2()  asm volatile("s_waitcnt vmcnt(2)" ::: "memory")
#define PRIO1() __builtin_amdgcn_s_setprio(1)
#define PRIO0() __builtin_amdgcn_s_setprio(0)

__global__ __launch_bounds__(512, 2) void gemm_8phase(const _Float16* __restrict__ Xh,
                                                      const _Float16* __restrict__ Wt,
                                                      const float* __restrict__ scale,
                                                      const float* __restrict__ bias,
                                                      float* __restrict__ C) {
    __shared__ __attribute__((aligned(128))) _Float16 As0_[16384];  // [256][64] f16
    __shared__ __attribute__((aligned(128))) _Float16 As1_[16384];
    __shared__ __attribute__((aligned(128))) _Float16 Bs0_[16384];
    __shared__ __attribute__((aligned(128))) _Float16 Bs1_[16384];

    // T1: XCD-aware bijective swizzle (512 blocks, 512 % 8 == 0)
    const int bid = blockIdx.x;
    const int swz = (bid & 7) * 64 + (bid >> 3);
    const int bm  = swz >> 4;            // 0..31
    const int bn  = swz & 15;            // 0..15

    const int t  = threadIdx.x;          // 0..511
    const int l  = t & 63;
    const int w  = t >> 6;               // 8 waves: 2(M) x 4(N)
    const int wm = w >> 2, wn = w & 3;   // wave block: 128 x 64
    const int lr = l & 15, lh = l >> 4;

    // staging: thread t covers row (t>>3)+{0,64} of each 128-row half, k-slot t&7.
    // T2 rule-21: linear LDS dest; SOURCE k pre-XORed by ((row&7)<<4) bytes.
    const int rowIdx = t >> 3;
    const int kbSw   = ((t & 7) * 16) ^ ((rowIdx & 7) << 4);
    const _Float16* aStageBase = Xh + (size_t)(bm * 256 + rowIdx) * K_DIM + (kbSw >> 1);
    const _Float16* bStageBase = Wt + (size_t)(bn * 256 + rowIdx) * K_DIM + (kbSw >> 1);

    // ds_read addresses (same XOR on the read side)
    const int  mask = (lr & 7) << 4;
    const uint32_t m6   = (uint32_t)(mask & 64);
    const uint32_t aoff = (uint32_t)((wm * 128 + lr) * 128 + ((lh * 16) ^ (mask & 48)));
    const uint32_t boff = (uint32_t)((wn * 64 + lr) * 128 + ((lh * 16) ^ (mask & 48)));
    const uint32_t aA0k0 = (uint32_t)(uintptr_t)As0_ + aoff + m6;
    const uint32_t aA0k1 = (uint32_t)(uintptr_t)As0_ + aoff + (64u ^ m6);
    const uint32_t aA1k0 = (uint32_t)(uintptr_t)As1_ + aoff + m6;
    const uint32_t aA1k1 = (uint32_t)(uintptr_t)As1_ + aoff + (64u ^ m6);
    const uint32_t bB0k0 = (uint32_t)(uintptr_t)Bs0_ + boff + m6;
    const uint32_t bB0k1 = (uint32_t)(uintptr_t)Bs0_ + boff + (64u ^ m6);
    const uint32_t bB1k0 = (uint32_t)(uintptr_t)Bs1_ + boff + m6;
    const uint32_t bB1k1 = (uint32_t)(uintptr_t)Bs1_ + boff + (64u ^ m6);

    f16x8 aq0[2][2], aq1[2][2], bf[4][2];
    f32x4 acc[8][4] = {};

    // prologue: stage K-tile 0 into buf0 (8 loads/wave outstanding)
    STAGE_A(As0_, 0, 0); STAGE_A(As0_, 1, 0);
    STAGE_B(Bs0_, 0, 0); STAGE_B(Bs0_, 1, 0);

#pragma unroll 1
    for (int i = 0; i < K_DIM / 128; ++i) {       // 32 iters, 2 K-tiles each
        const int t1 = 2 * i + 1;                 // <= 63
        const int t2 = (2 * i + 2) & 63;          // wraps only on last iter (data unused)
        // ---- K-tile 2i (buf0), staging tile t1 into buf1 (1/2/1/0) ----
        // ph0
        STAGE_A(As1_, 0, t1);
        VMC2(); BARR();                           // buf0's 8 loads landed, all waves
        DSRB(bB0k0, bB0k1);                       // 8 B reads
        DSRA(aq0, 0, aA0k0, aA0k1);               // quad0 -> aq0
        DSRA(aq1, 1, aA0k0, aA0k1);               // quad1 -> aq1 (prefetch)
        LGKM4();                                  // B + quad0 ready, quad1 in flight
        PRIO1(); MFMA16(0, aq0); PRIO0(); BARR();
        // ph1
        DSRA(aq0, 2, aA0k0, aA0k1);               // quad2 -> aq0 (under our MFMA shadow)
        STAGE_A(As1_, 1, t1); STAGE_B(Bs1_, 0, t1);
        BARR(); LGKM4();                          // quad1 ready
        PRIO1(); MFMA16(1, aq1); PRIO0(); BARR();
        // ph2
        DSRA(aq1, 3, aA0k0, aA0k1);               // quad3 -> aq1
        STAGE_B(Bs1_, 1, t1);
        BARR(); LGKM4();                          // quad2 ready
        PRIO1(); MFMA16(2, aq0); PRIO0(); BARR();
        // ph3
        LGKM0();                                  // quad3 ready
        PRIO1(); MFMA16(3, aq1); PRIO0(); BARR();
        // ---- K-tile 2i+1 (buf1), staging tile t2 into buf0 (1/2/1/0) ----
        // ph4
        STAGE_A(As0_, 0, t2);
        VMC2(); BARR();                           // buf1's 8 loads landed
        DSRB(bB1k0, bB1k1);
        DSRA(aq0, 0, aA1k0, aA1k1);
        DSRA(aq1, 1, aA1k0, aA1k1);
        LGKM4();
        PRIO1(); MFMA16(0, aq0); PRIO0(); BARR();
        // ph5
        DSRA(aq0, 2, aA1k0, aA1k1);
        STAGE_A(As0_, 1, t2); STAGE_B(Bs0_, 0, t2);
        BARR(); LGKM4();
        PRIO1(); MFMA16(1, aq1); PRIO0(); BARR();
        // ph6
        DSRA(aq1, 3, aA1k0, aA1k1);
        STAGE_B(Bs0_, 1, t2);
        BARR(); LGKM4();
        PRIO1(); MFMA16(2, aq0); PRIO0(); BARR();
        // ph7
        LGKM0();
        PRIO1(); MFMA16(3, aq1); PRIO0(); BARR();
    }
    asm volatile("s_waitcnt vmcnt(0)" ::: "memory");  // drain dangling prefetch

    // epilogue: C/D layout col = lane&15, row = (lane>>4)*4 + reg  [m89-verified]
    const int col0 = bn * 256 + wn * 64 + lr;
    const int row0 = bm * 256 + wm * 128 + lh * 4;
    float sc[4], bi[4];
#pragma unroll
    for (int ni = 0; ni < 4; ++ni) {
        sc[ni] = scale[col0 + ni * 16];
        bi[ni] = bias[col0 + ni * 16];
    }
#pragma unroll
    for (int ai = 0; ai < 8; ++ai)
#pragma unroll
        for (int r = 0; r < 4; ++r) {
            const size_t rowOff = (size_t)(row0 + ai * 16 + r) * N_DIM;
#pragma unroll
            for (int ni = 0; ni < 4; ++ni)
                C[rowOff + col0 + ni * 16] = acc[ai][ni][r] * sc[ni] + bi[ni];
        }
}

extern "C" void kernel_launch(void* const* d_in, const int* in_sizes, int n_in,
                              void* d_out, int out_size, void* d_ws, size_t ws_size,
                              hipStream_t stream) {
    const float* x     = (const float*)d_in[0];
    const int*   wq    = (const int*)d_in[1];
    const float* scale = (const float*)d_in[2];
    const float* bias  = (const float*)d_in[3];
    float* out = (float*)d_out;

    const size_t needW = (size_t)N_DIM * K_DIM * sizeof(_Float16);   // 33.5 MB
    _Float16* Wt = (_Float16*)d_ws;
    _Float16* Xh = (_Float16*)((char*)d_ws + needW);                 // ws >= 100.7MB (r4)

    dim3 tgrid(N_DIM / 64, K_DIM / 64);
    dequant_w_to_f16<<<tgrid, 256, 0, stream>>>(wq, Wt);
    convert_x_to_f16<<<((size_t)M_DIM * K_DIM) / (256 * 8), 256, 0, stream>>>(x, Xh);

    const int nblocks = (M_DIM / 256) * (N_DIM / 256);               // 512
    gemm_8phase<<<nblocks, 512, 0, stream>>>(Xh, Wt, scale, bias, out);
}

// Round 7
// 274.038 us; speedup vs baseline: 1.0153x; 1.0153x over previous
//
#include <hip/hip_runtime.h>
#include <stdint.h>

// EETQLinear w8a16: out[m,n] = (sum_k x[m,k]*wq[k,n]) * scale[n] + bias[n]
// M=8192, K=4096, N=4096. Dtypes (r3/r4-verified): x/scale/bias/out f32, wq int32.
// v7: minimum-barrier schedule — 2 barriers per K-tile (DMA-landed broadcast +
//     buffer-free broadcast). Intra-tile lockstep removed; waves drift so MFMA
//     clusters of different waves overlap other waves' issue sections.
//     Keeps: T1 XCD swizzle, T2 both-sides XOR swizzle (conflicts=0, r5-verified),
//     counted vmcnt(2) (never 0 in loop), counted lgkm, ping-pong A-frag regs, T5.

typedef __attribute__((ext_vector_type(4))) float     f32x4;
typedef __attribute__((ext_vector_type(8))) _Float16  f16x8;

#define M_DIM 8192
#define N_DIM 4096
#define K_DIM 4096

// ---------------- prologue kernels (r4-verified) ----------------
__global__ __launch_bounds__(256) void convert_x_to_f16(const float* __restrict__ x,
                                                        _Float16* __restrict__ Xh) {
    const size_t i = ((size_t)blockIdx.x * 256 + threadIdx.x) * 8;
    float4 v0 = *(const float4*)(x + i);
    float4 v1 = *(const float4*)(x + i + 4);
    f16x8 h;
    h[0] = (_Float16)v0.x; h[1] = (_Float16)v0.y; h[2] = (_Float16)v0.z; h[3] = (_Float16)v0.w;
    h[4] = (_Float16)v1.x; h[5] = (_Float16)v1.y; h[6] = (_Float16)v1.z; h[7] = (_Float16)v1.w;
    *(f16x8*)(Xh + i) = h;
}

__global__ __launch_bounds__(256) void dequant_w_to_f16(const int* __restrict__ wq,
                                                        _Float16* __restrict__ Wt) {
    __shared__ _Float16 tile[64][65];
    const int n0 = blockIdx.x * 64;
    const int k0 = blockIdx.y * 64;
    const int t  = threadIdx.x;
    const int r  = t >> 2;
    const int c0 = (t & 3) * 16;
    const int* src = wq + (size_t)(k0 + r) * N_DIM + n0 + c0;
#pragma unroll
    for (int j = 0; j < 4; ++j) {
        int4 q = *(const int4*)(src + j * 4);
        tile[c0 + j * 4 + 0][r] = (_Float16)q.x;
        tile[c0 + j * 4 + 1][r] = (_Float16)q.y;
        tile[c0 + j * 4 + 2][r] = (_Float16)q.z;
        tile[c0 + j * 4 + 3][r] = (_Float16)q.w;
    }
    __syncthreads();
    const int nn  = t >> 2;
    const int cc0 = (t & 3) * 16;
    _Float16 vals[16] __attribute__((aligned(16)));
#pragma unroll
    for (int j = 0; j < 16; ++j) vals[j] = tile[nn][cc0 + j];
    _Float16* dst = Wt + (size_t)(n0 + nn) * K_DIM + k0 + cc0;
    *(float4*)(dst + 0) = *(const float4*)(vals + 0);
    *(float4*)(dst + 8) = *(const float4*)(vals + 8);
}

// ---------------- minimum-barrier 256x256 GEMM ----------------
#define AS1C(p) (const __attribute__((address_space(1))) void*)(p)
#define AS3C(p) (__attribute__((address_space(3))) void*)(p)

#define STAGE_A(arr, h, tile) do {                                                    \
    __builtin_amdgcn_global_load_lds(                                                 \
        AS1C(aStageBase + (size_t)((h) * 128) * K_DIM + (tile) * 64),                 \
        AS3C((char*)(arr) + (h) * 16384 + t * 16), 16, 0, 0);                         \
    __builtin_amdgcn_global_load_lds(                                                 \
        AS1C(aStageBase + (size_t)((h) * 128 + 64) * K_DIM + (tile) * 64),            \
        AS3C((char*)(arr) + (h) * 16384 + 8192 + t * 16), 16, 0, 0);                  \
} while (0)

#define STAGE_B(arr, h, tile) do {                                                    \
    __builtin_amdgcn_global_load_lds(                                                 \
        AS1C(bStageBase + (size_t)((h) * 128) * K_DIM + (tile) * 64),                 \
        AS3C((char*)(arr) + (h) * 16384 + t * 16), 16, 0, 0);                         \
    __builtin_amdgcn_global_load_lds(                                                 \
        AS1C(bStageBase + (size_t)((h) * 128 + 64) * K_DIM + (tile) * 64),            \
        AS3C((char*)(arr) + (h) * 16384 + 8192 + t * 16), 16, 0, 0);                  \
} while (0)

#define DSR(dst, addr, IMM) \
    asm volatile("ds_read_b128 %0, %1 offset:%c2" : "=v"(dst) : "v"(addr), "i"(IMM))

#define DSRA(S, Q, A0, A1)                   \
    DSR(S[0][0], A0, (Q) * 4096);            \
    DSR(S[0][1], A1, (Q) * 4096);            \
    DSR(S[1][0], A0, (Q) * 4096 + 2048);     \
    DSR(S[1][1], A1, (Q) * 4096 + 2048)

#define DSRB(BA0, BA1)                       \
    DSR(bf[0][0], BA0, 0);    DSR(bf[0][1], BA1, 0);    \
    DSR(bf[1][0], BA0, 2048); DSR(bf[1][1], BA1, 2048); \
    DSR(bf[2][0], BA0, 4096); DSR(bf[2][1], BA1, 4096); \
    DSR(bf[3][0], BA0, 6144); DSR(bf[3][1], BA1, 6144)

#define MMS(S, AI, N)                                                                 \
    acc[AI][N] = __builtin_amdgcn_mfma_f32_16x16x32_f16(S[(AI) & 1][0], bf[N][0],     \
                                                        acc[AI][N], 0, 0, 0);         \
    acc[AI][N] = __builtin_amdgcn_mfma_f32_16x16x32_f16(S[(AI) & 1][1], bf[N][1],     \
                                                        acc[AI][N], 0, 0, 0)

#define MFMA16(Q, S)                                                  \
    MMS(S, (Q) * 2 + 0, 0); MMS(S, (Q) * 2 + 0, 1);                   \
    MMS(S, (Q) * 2 + 0, 2); MMS(S, (Q) * 2 + 0, 3);                   \
    MMS(S, (Q) * 2 + 1, 0); MMS(S, (Q) * 2 + 1, 1);                   \
    MMS(S, (Q) * 2 + 1, 2); MMS(S, (Q) * 2 + 1, 3)

#define BARR()  __builtin_amdgcn_s_barrier()
#define SB0()   __builtin_amdgcn_sched_barrier(0)
#define LGKM0() do { asm volatile("s_waitcnt lgkmcnt(0)" ::: "memory"); SB0(); } while (0)
#define LGKM4() do { asm volatile("s_waitcnt lgkmcnt(4)" ::: "memory"); SB0(); } while (0)
#define VMC2()  asm volatile("s_waitcnt vmcnt(2)" ::: "memory")
#define PRIO1() __builtin_amdgcn_s_setprio(1)
#define PRIO0() __builtin_amdgcn_s_setprio(0)

// One K-tile: read (Arr,B0k0,B0k1), stage tile `tl` into the OTHER pair (Adst,Bdst).
// Barriers: 1 after VMC2 (DMA-landed broadcast), 1 at end (buffer-free broadcast).
#define KTILE(A0, A1, B0, B1, Adst, Bdst, tl) do {                                    \
    STAGE_A(Adst, 0, tl);                   /* dst pair freed by prev end-BARR */     \
    VMC2();                                 /* my 8 loads of THIS tile landed */      \
    BARR();                                 /* ... and everyone else's */             \
    DSRB(B0, B1);                                                                     \
    DSRA(aq0, 0, A0, A1);                                                             \
    DSRA(aq1, 1, A0, A1);                                                             \
    LGKM4();  PRIO1(); MFMA16(0, aq0); PRIO0();                                       \
    DSRA(aq0, 2, A0, A1);  STAGE_A(Adst, 1, tl);                                      \
    LGKM4();  PRIO1(); MFMA16(1, aq1); PRIO0();                                       \
    DSRA(aq1, 3, A0, A1);  STAGE_B(Bdst, 0, tl);                                      \
    LGKM4();  PRIO1(); MFMA16(2, aq0); PRIO0();                                       \
    STAGE_B(Bdst, 1, tl);                                                             \
    LGKM0();  PRIO1(); MFMA16(3, aq1); PRIO0();                                       \
    BARR();                                 /* all waves done reading this pair */    \
} while (0)

__global__ __launch_bounds__(512, 2) void gemm_8phase(const _Float16* __restrict__ Xh,
                                                      const _Float16* __restrict__ Wt,
                                                      const float* __restrict__ scale,
                                                      const float* __restrict__ bias,
                                                      float* __restrict__ C) {
    __shared__ __attribute__((aligned(128))) _Float16 As0_[16384];  // [256][64] f16
    __shared__ __attribute__((aligned(128))) _Float16 As1_[16384];
    __shared__ __attribute__((aligned(128))) _Float16 Bs0_[16384];
    __shared__ __attribute__((aligned(128))) _Float16 Bs1_[16384];

    // T1: XCD-aware bijective swizzle (512 blocks, 512 % 8 == 0)
    const int bid = blockIdx.x;
    const int swz = (bid & 7) * 64 + (bid >> 3);
    const int bm  = swz >> 4;            // 0..31
    const int bn  = swz & 15;            // 0..15

    const int t  = threadIdx.x;          // 0..511
    const int l  = t & 63;
    const int w  = t >> 6;               // 8 waves: 2(M) x 4(N)
    const int wm = w >> 2, wn = w & 3;   // wave block: 128 x 64
    const int lr = l & 15, lh = l >> 4;

    // staging: thread t covers rows (t>>3)+{0,64} of each 128-row half, k-slot t&7.
    // T2 rule-21: linear LDS dest; SOURCE k pre-XORed by ((row&7)<<4) bytes.
    const int rowIdx = t >> 3;
    const int kbSw   = ((t & 7) * 16) ^ ((rowIdx & 7) << 4);
    const _Float16* aStageBase = Xh + (size_t)(bm * 256 + rowIdx) * K_DIM + (kbSw >> 1);
    const _Float16* bStageBase = Wt + (size_t)(bn * 256 + rowIdx) * K_DIM + (kbSw >> 1);

    // ds_read addresses (same XOR on the read side)
    const int  mask = (lr & 7) << 4;
    const uint32_t m6   = (uint32_t)(mask & 64);
    const uint32_t aoff = (uint32_t)((wm * 128 + lr) * 128 + ((lh * 16) ^ (mask & 48)));
    const uint32_t boff = (uint32_t)((wn * 64 + lr) * 128 + ((lh * 16) ^ (mask & 48)));
    const uint32_t aA0k0 = (uint32_t)(uintptr_t)As0_ + aoff + m6;
    const uint32_t aA0k1 = (uint32_t)(uintptr_t)As0_ + aoff + (64u ^ m6);
    const uint32_t aA1k0 = (uint32_t)(uintptr_t)As1_ + aoff + m6;
    const uint32_t aA1k1 = (uint32_t)(uintptr_t)As1_ + aoff + (64u ^ m6);
    const uint32_t bB0k0 = (uint32_t)(uintptr_t)Bs0_ + boff + m6;
    const uint32_t bB0k1 = (uint32_t)(uintptr_t)Bs0_ + boff + (64u ^ m6);
    const uint32_t bB1k0 = (uint32_t)(uintptr_t)Bs1_ + boff + m6;
    const uint32_t bB1k1 = (uint32_t)(uintptr_t)Bs1_ + boff + (64u ^ m6);

    f16x8 aq0[2][2], aq1[2][2], bf[4][2];
    f32x4 acc[8][4] = {};

    // prologue: stage K-tile 0 into buf0 (8 loads/wave outstanding)
    STAGE_A(As0_, 0, 0); STAGE_A(As0_, 1, 0);
    STAGE_B(Bs0_, 0, 0); STAGE_B(Bs0_, 1, 0);

#pragma unroll 1
    for (int i = 0; i < K_DIM / 128; ++i) {       // 32 iters, 2 K-tiles each
        const int t1 = 2 * i + 1;                 // <= 63
        const int t2 = (2 * i + 2) & 63;          // wraps only on last iter (data unused)
        KTILE(aA0k0, aA0k1, bB0k0, bB0k1, As1_, Bs1_, t1);   // tile 2i   (buf0)
        KTILE(aA1k0, aA1k1, bB1k0, bB1k1, As0_, Bs0_, t2);   // tile 2i+1 (buf1)
    }
    asm volatile("s_waitcnt vmcnt(0)" ::: "memory");  // drain dangling prefetch

    // epilogue: C/D layout col = lane&15, row = (lane>>4)*4 + reg  [m89-verified]
    const int col0 = bn * 256 + wn * 64 + lr;
    const int row0 = bm * 256 + wm * 128 + lh * 4;
    float sc[4], bi[4];
#pragma unroll
    for (int ni = 0; ni < 4; ++ni) {
        sc[ni] = scale[col0 + ni * 16];
        bi[ni] = bias[col0 + ni * 16];
    }
#pragma unroll
    for (int ai = 0; ai < 8; ++ai)
#pragma unroll
        for (int r = 0; r < 4; ++r) {
            const size_t rowOff = (size_t)(row0 + ai * 16 + r) * N_DIM;
#pragma unroll
            for (int ni = 0; ni < 4; ++ni)
                C[rowOff + col0 + ni * 16] = acc[ai][ni][r] * sc[ni] + bi[ni];
        }
}

extern "C" void kernel_launch(void* const* d_in, const int* in_sizes, int n_in,
                              void* d_out, int out_size, void* d_ws, size_t ws_size,
                              hipStream_t stream) {
    const float* x     = (const float*)d_in[0];
    const int*   wq    = (const int*)d_in[1];
    const float* scale = (const float*)d_in[2];
    const float* bias  = (const float*)d_in[3];
    float* out = (float*)d_out;

    const size_t needW = (size_t)N_DIM * K_DIM * sizeof(_Float16);   // 33.5 MB
    _Float16* Wt = (_Float16*)d_ws;
    _Float16* Xh = (_Float16*)((char*)d_ws + needW);                 // ws >= 100.7MB (r4)

    dim3 tgrid(N_DIM / 64, K_DIM / 64);
    dequant_w_to_f16<<<tgrid, 256, 0, stream>>>(wq, Wt);
    convert_x_to_f16<<<((size_t)M_DIM * K_DIM) / (256 * 8), 256, 0, stream>>>(x, Xh);

    const int nblocks = (M_DIM / 256) * (N_DIM / 256);               // 512
    gemm_8phase<<<nblocks, 512, 0, stream>>>(Xh, Wt, scale, bias, out);
}